// Round 12
// baseline (26284.232 us; speedup 1.0000x reference)
//
#include <hip/hip_runtime.h>

#define T_STEPS 65536
#define NIN 99
#define HID 64
#define G4 256   // 4*HID gates
#define TS 128   // timesteps per block in the projection kernel

// ---------------- Kernel 1: xz[t][gate] = W_ih[gate].x[t] + b_ih + b_hh ----------------
__global__ __launch_bounds__(256, 1) void xz_kernel(
    const float* __restrict__ x, const float* __restrict__ W_ih,
    const float* __restrict__ b_ih, const float* __restrict__ b_hh,
    float* __restrict__ xz) {
    __shared__ __align__(16) float xs[TS * 100];   // padded rows: 400 B stride
    const int g  = threadIdx.x;                    // gate row 0..255
    const int t0 = blockIdx.x * TS;

    for (int i = g; i < TS * NIN; i += 256) {
        int tl = i / NIN;
        int j  = i - tl * NIN;
        xs[tl * 100 + j] = x[(size_t)t0 * NIN + i];
    }

    float w[NIN];
#pragma unroll
    for (int j = 0; j < NIN; ++j) w[j] = W_ih[g * NIN + j];
    const float bias = b_ih[g] + b_hh[g];
    __syncthreads();

    for (int tl = 0; tl < TS; ++tl) {
        const float* xr = &xs[tl * 100];
        float a0 = bias, a1 = 0.f, a2 = 0.f, a3 = 0.f;
#pragma unroll
        for (int j4 = 0; j4 < 24; ++j4) {
            float4 xv = *(const float4*)(xr + 4 * j4);
            a0 = fmaf(w[4 * j4 + 0], xv.x, a0);
            a1 = fmaf(w[4 * j4 + 1], xv.y, a1);
            a2 = fmaf(w[4 * j4 + 2], xv.z, a2);
            a3 = fmaf(w[4 * j4 + 3], xv.w, a3);
        }
        a0 = fmaf(w[96], xr[96], a0);
        a1 = fmaf(w[97], xr[97], a1);
        a2 = fmaf(w[98], xr[98], a2);
        xz[(size_t)(t0 + tl) * G4 + g] = (a0 + a1) + (a2 + a3);
    }
}

// ---------------- Kernel 2: output-stationary LSTM, full-asm ----------------
// Wave w owns gate type w (0=i,1=f,2=g,3=o); lane l owns unit l.
// Per step: 64 v_readlane (inline lanes) + 64 v_fmac (full 64-k dot of gate
// row 64w+l), ONE activation (wave-uniform type via A*(rcp(1+exp2(S*x))+D)),
// 1 ds_write_b32 + lgkm-only barrier + 2 ds_read2_b32, replicated c/h update.
// Registers: v64-127 weights, v196 h, v197 c, v199 zptr, v200-203 acc,
// v204-207 gates(i,f,g,o), v210-212 scratch, v224-227 z ring.

#define RL(S,L) "v_readlane_b32 s" #S ", v196, " #L "\n\t"
#define FM(A,S,W) "v_fmac_f32 v" #A ", s" #S ", v" #W "\n\t"
#define FML(A,S,W) "v_mul_f32 v" #A ", s" #S ", v" #W "\n\t"

#define RL_ALL \
  RL(8,0) RL(9,1) RL(10,2) RL(11,3) RL(12,4) RL(13,5) RL(14,6) RL(15,7) \
  RL(16,8) RL(17,9) RL(18,10) RL(19,11) RL(20,12) RL(21,13) RL(22,14) RL(23,15) \
  RL(24,16) RL(25,17) RL(26,18) RL(27,19) RL(28,20) RL(29,21) RL(30,22) RL(31,23) \
  RL(32,24) RL(33,25) RL(34,26) RL(35,27) RL(36,28) RL(37,29) RL(38,30) RL(39,31) \
  RL(40,32) RL(41,33) RL(42,34) RL(43,35) RL(44,36) RL(45,37) RL(46,38) RL(47,39) \
  RL(48,40) RL(49,41) RL(50,42) RL(51,43) RL(52,44) RL(53,45) RL(54,46) RL(55,47) \
  RL(56,48) RL(57,49) RL(58,50) RL(59,51) RL(60,52) RL(61,53) RL(62,54) RL(63,55) \
  RL(64,56) RL(65,57) RL(66,58) RL(67,59) RL(68,60) RL(69,61) RL(70,62) RL(71,63)

#define FM_ALL \
  FML(200,8,64) FML(201,9,65) FML(202,10,66) FML(203,11,67) \
  FM(200,12,68) FM(201,13,69) FM(202,14,70) FM(203,15,71) \
  FM(200,16,72) FM(201,17,73) FM(202,18,74) FM(203,19,75) \
  FM(200,20,76) FM(201,21,77) FM(202,22,78) FM(203,23,79) \
  FM(200,24,80) FM(201,25,81) FM(202,26,82) FM(203,27,83) \
  FM(200,28,84) FM(201,29,85) FM(202,30,86) FM(203,31,87) \
  FM(200,32,88) FM(201,33,89) FM(202,34,90) FM(203,35,91) \
  FM(200,36,92) FM(201,37,93) FM(202,38,94) FM(203,39,95) \
  FM(200,40,96) FM(201,41,97) FM(202,42,98) FM(203,43,99) \
  FM(200,44,100) FM(201,45,101) FM(202,46,102) FM(203,47,103) \
  FM(200,48,104) FM(201,49,105) FM(202,50,106) FM(203,51,107) \
  FM(200,52,108) FM(201,53,109) FM(202,54,110) FM(203,55,111) \
  FM(200,56,112) FM(201,57,113) FM(202,58,114) FM(203,59,115) \
  FM(200,60,116) FM(201,61,117) FM(202,62,118) FM(203,63,119) \
  FM(200,64,120) FM(201,65,121) FM(202,66,122) FM(203,67,123) \
  FM(200,68,124) FM(201,69,125) FM(202,70,126) FM(203,71,127)

// one timestep: WOFS = ds byte offset for parity, RA = read-addr reg, ZR = z ring reg
#define STEP(WOFS, RA, ZR) \
  RL_ALL \
  FM_ALL \
  "s_waitcnt vmcnt(3)\n\t" \
  "v_add_f32 v200, v200, v201\n\t" \
  "v_add_f32 v202, v202, v203\n\t" \
  "v_add_f32 v200, v200, " ZR "\n\t" \
  "global_load_dword " ZR ", v199, %[zb]\n\t" \
  "v_add_u32 v199, 0x400, v199\n\t" \
  "v_cmp_gt_u32 vcc, 0x4000000, v199\n\t" \
  "v_cndmask_b32 v199, %[zoff], v199, vcc\n\t" \
  "v_add_f32 v200, v200, v202\n\t" \
  /* act = aA * (rcp(1 + exp2(aS*x)) + aD)  (sigmoid or tanh, wave-uniform) */ \
  "v_mul_f32 v210, %[aS], v200\n\t" \
  "v_exp_f32 v210, v210\n\t" \
  "s_nop 0\n\t" \
  "v_add_f32 v210, 1.0, v210\n\t" \
  "v_rcp_f32 v210, v210\n\t" \
  "s_nop 0\n\t" \
  "v_add_f32 v210, %[aD], v210\n\t" \
  "v_mul_f32 v210, %[aA], v210\n\t" \
  /* exchange activated gates */ \
  "ds_write_b32 %[wa], v210 offset:" WOFS "\n\t" \
  "s_waitcnt lgkmcnt(0)\n\t" \
  "s_barrier\n\t" \
  "ds_read2_b32 v[204:205], " RA " offset0:0 offset1:64\n\t" \
  "ds_read2_b32 v[206:207], " RA " offset0:128 offset1:192\n\t" \
  "s_waitcnt lgkmcnt(0)\n\t" \
  /* c = f*c + i*g ; h = o * tanh(c) */ \
  "v_mul_f32 v211, v204, v206\n\t" \
  "v_fma_f32 v197, v205, v197, v211\n\t" \
  "v_mul_f32 v212, 0xc038aa3b, v197\n\t" \
  "v_exp_f32 v212, v212\n\t" \
  "s_nop 0\n\t" \
  "v_add_f32 v212, 1.0, v212\n\t" \
  "v_rcp_f32 v212, v212\n\t" \
  "s_nop 0\n\t" \
  "v_fma_f32 v212, 2.0, v212, -1.0\n\t" \
  "v_mul_f32 v196, v207, v212\n\t"

__global__ __launch_bounds__(256, 1) __attribute__((amdgpu_waves_per_eu(1)))
void lstm_kernel(
    const float* __restrict__ xz, const float* __restrict__ W_hh,
    const float* __restrict__ W1, const float* __restrict__ W2,
    const float* __restrict__ b2, float* __restrict__ out) {
    __shared__ __align__(16) float gbuf[2][4][HID];   // [parity][type][unit]
    __shared__ float hfin[HID];
    __shared__ float hbuf[32];
    const int tid = threadIdx.x;
    const int l   = tid & 63;
    const int wv  = tid >> 6;

    unsigned woff = (unsigned)(tid * 256);           // W_hh row 64wv+l, 256 B/row
    unsigned zoff = (unsigned)(tid * 4);             // xz[t][gate=tid]
    unsigned lbase = (unsigned)(size_t)&gbuf[0][0][0];
    unsigned wa  = lbase + (unsigned)(wv * 256 + l * 4);   // write: own type slot
    unsigned ra0 = lbase + (unsigned)(l * 4);              // read base, parity 0
    unsigned ra1 = lbase + 1024u + (unsigned)(l * 4);      // read base, parity 1

    // wave-uniform activation constants: waves 0,1,3 sigmoid; wave 2 tanh
    float aS = (wv == 2) ? -2.8853901f : -1.4426950f;  // -2log2e / -log2e
    float aA = (wv == 2) ? 2.0f : 1.0f;
    float aD = (wv == 2) ? -0.5f : 0.0f;

    float h;
    asm volatile(
        // ---- prologue: h=c=0, weights -> v64..v127, z ring -> v224..v227 ----
        "v_mov_b32 v196, 0\n\t"
        "v_mov_b32 v197, 0\n\t"
        "v_mov_b32 v199, %[woff]\n\t"
        "global_load_dwordx4 v[64:67],   v199, %[wb]\n\t"
        "global_load_dwordx4 v[68:71],   v199, %[wb] offset:16\n\t"
        "global_load_dwordx4 v[72:75],   v199, %[wb] offset:32\n\t"
        "global_load_dwordx4 v[76:79],   v199, %[wb] offset:48\n\t"
        "global_load_dwordx4 v[80:83],   v199, %[wb] offset:64\n\t"
        "global_load_dwordx4 v[84:87],   v199, %[wb] offset:80\n\t"
        "global_load_dwordx4 v[88:91],   v199, %[wb] offset:96\n\t"
        "global_load_dwordx4 v[92:95],   v199, %[wb] offset:112\n\t"
        "global_load_dwordx4 v[96:99],   v199, %[wb] offset:128\n\t"
        "global_load_dwordx4 v[100:103], v199, %[wb] offset:144\n\t"
        "global_load_dwordx4 v[104:107], v199, %[wb] offset:160\n\t"
        "global_load_dwordx4 v[108:111], v199, %[wb] offset:176\n\t"
        "global_load_dwordx4 v[112:115], v199, %[wb] offset:192\n\t"
        "global_load_dwordx4 v[116:119], v199, %[wb] offset:208\n\t"
        "global_load_dwordx4 v[120:123], v199, %[wb] offset:224\n\t"
        "global_load_dwordx4 v[124:127], v199, %[wb] offset:240\n\t"
        "v_mov_b32 v199, %[zoff]\n\t"
        "global_load_dword v224, v199, %[zb]\n\t"
        "global_load_dword v225, v199, %[zb] offset:1024\n\t"
        "global_load_dword v226, v199, %[zb] offset:2048\n\t"
        "global_load_dword v227, v199, %[zb] offset:3072\n\t"
        "v_add_u32 v199, 0x1000, v199\n\t"
        "s_waitcnt vmcnt(4)\n\t"            // weights resident; z ring in flight
        "s_mov_b32 s85, 0x4000\n\t"         // 16384 iterations x 4 steps
        "LSTM%=:\n\t"
        STEP("0",    "%[ra0]", "v224")
        STEP("1024", "%[ra1]", "v225")
        STEP("0",    "%[ra0]", "v226")
        STEP("1024", "%[ra1]", "v227")
        "s_sub_u32 s85, s85, 1\n\t"
        "s_cmp_lg_u32 s85, 0\n\t"
        "s_cbranch_scc1 LSTM%=\n\t"
        "v_mov_b32 %[hout], v196\n\t"
        : [hout]"=v"(h)
        : [wb]"s"(W_hh), [zb]"s"(xz),
          [woff]"v"(woff), [zoff]"v"(zoff),
          [wa]"v"(wa), [ra0]"v"(ra0), [ra1]"v"(ra1),
          [aS]"s"(aS), [aA]"s"(aA), [aD]"s"(aD)
        : "memory", "vcc",
          "s8","s9","s10","s11","s12","s13","s14","s15",
          "s16","s17","s18","s19","s20","s21","s22","s23",
          "s24","s25","s26","s27","s28","s29","s30","s31",
          "s32","s33","s34","s35","s36","s37","s38","s39",
          "s40","s41","s42","s43","s44","s45","s46","s47",
          "s48","s49","s50","s51","s52","s53","s54","s55",
          "s56","s57","s58","s59","s60","s61","s62","s63",
          "s64","s65","s66","s67","s68","s69","s70","s71",
          "s85",
          "v64","v65","v66","v67","v68","v69","v70","v71",
          "v72","v73","v74","v75","v76","v77","v78","v79",
          "v80","v81","v82","v83","v84","v85","v86","v87",
          "v88","v89","v90","v91","v92","v93","v94","v95",
          "v96","v97","v98","v99","v100","v101","v102","v103",
          "v104","v105","v106","v107","v108","v109","v110","v111",
          "v112","v113","v114","v115","v116","v117","v118","v119",
          "v120","v121","v122","v123","v124","v125","v126","v127",
          "v196","v197","v199",
          "v200","v201","v202","v203","v204","v205","v206","v207",
          "v210","v211","v212",
          "v224","v225","v226","v227");

    // head: out = W2 @ relu(W1 @ relu(h_T)) + b2
    if (tid < HID) hfin[tid] = h;
    __syncthreads();
    if (tid < 32) {
        float s = 0.0f;
#pragma unroll
        for (int j = 0; j < HID; ++j) s += W1[tid * HID + j] * fmaxf(hfin[j], 0.0f);
        hbuf[tid] = fmaxf(s, 0.0f);
    }
    __syncthreads();
    if (tid < 3) {
        float s = b2[tid];
#pragma unroll
        for (int j = 0; j < 32; ++j) s += W2[tid * 32 + j] * hbuf[j];
        out[tid] = s;
    }
}

extern "C" void kernel_launch(void* const* d_in, const int* in_sizes, int n_in,
                              void* d_out, int out_size, void* d_ws, size_t ws_size,
                              hipStream_t stream) {
    const float* x   = (const float*)d_in[0];
    const float* Wih = (const float*)d_in[1];
    const float* Whh = (const float*)d_in[2];
    const float* bih = (const float*)d_in[3];
    const float* bhh = (const float*)d_in[4];
    const float* W1  = (const float*)d_in[5];
    const float* W2  = (const float*)d_in[6];
    const float* b2  = (const float*)d_in[7];
    float* out = (float*)d_out;
    float* xz  = (float*)d_ws;   // T_STEPS * 256 floats = 64 MB

    xz_kernel<<<T_STEPS / TS, 256, 0, stream>>>(x, Wih, bih, bhh, xz);
    lstm_kernel<<<1, 256, 0, stream>>>(xz, Whh, W1, W2, b2, out);
}